// Round 11
// baseline (156.810 us; speedup 1.0000x reference)
//
#include <hip/hip_runtime.h>

typedef __attribute__((ext_vector_type(8))) short short8;
typedef __attribute__((ext_vector_type(4))) float f32x4;
typedef __attribute__((ext_vector_type(4))) unsigned int u32x4;
typedef unsigned short ushort_t;

constexpr int B   = 4;
constexpr int C   = 256;
constexpr int H   = 64;
constexpr int W   = 64;
constexpr int HW  = H * W;          // 4096
constexpr int OCH = 256;
constexpr int KT  = 9 * C;          // 2304, k order: k = tap*256 + c
constexpr int NHS = KT / 32;        // 72 half-steps (MFMA K=32)

__device__ __forceinline__ ushort_t f2bf(float f) {
    unsigned u = __float_as_uint(f);
    u += 0x7FFF + ((u >> 16) & 1);      // RNE
    return (ushort_t)(u >> 16);
}

// Barrier that does NOT drain vmcnt: LDS writes are made visible
// (lgkmcnt(0)), but in-register global loads stay in flight across it.
__device__ __forceinline__ void block_sync_lds() {
    asm volatile("s_waitcnt lgkmcnt(0)" ::: "memory");
    __builtin_amdgcn_s_barrier();
    asm volatile("" ::: "memory");
}

// ---------------------------------------------------------------------------
// K1: merged weight packing.
//  tid < 73728 : wPack  (w_def A-fragment order, validated rounds 2-10)
//  else        : wOffA  (w_off A-fragment order, M padded 18->32)
// ---------------------------------------------------------------------------
__global__ __launch_bounds__(256) void pack_all(
    const float* __restrict__ w_def, const float* __restrict__ w_off,
    ushort_t* __restrict__ wPack, ushort_t* __restrict__ wOffA)
{
    int tid = blockIdx.x * 256 + threadIdx.x;
    if (tid < NHS * 16 * 64) {
        int lane = tid & 63;
        int o = ((tid >> 6) & 15) * 16 + (lane & 15);
        int kbase = (tid >> 10) * 32 + (lane >> 4) * 8;
        union { ushort_t u[8]; short8 v; } pk;
        #pragma unroll
        for (int j = 0; j < 8; ++j) {
            int kidx = kbase + j;
            int c = kidx & 255, tap = kidx >> 8;
            pk.u[j] = f2bf(w_def[((size_t)o * C + c) * 9 + tap]);
        }
        *(short8*)(wPack + (size_t)tid * 8) = pk.v;
    } else {
        int t2 = tid - NHS * 16 * 64;
        if (t2 >= NHS * 2 * 64) return;
        int lane = t2 & 63;
        int o = ((t2 >> 6) & 1) * 16 + (lane & 15);
        int kbase = (t2 >> 7) * 32 + (lane >> 4) * 8;
        union { ushort_t u[8]; short8 v; } pk;
        #pragma unroll
        for (int j = 0; j < 8; ++j) {
            int kidx = kbase + j;
            int c = kidx & 255, tap = kidx >> 8;
            pk.u[j] = (o < 18) ? f2bf(w_off[((size_t)o * C + c) * 9 + tap]) : (ushort_t)0;
        }
        *(short8*)(wOffA + (size_t)t2 * 8) = pk.v;
    }
}

// ---------------------------------------------------------------------------
// K0: transpose ALL batches: xt[b][y][x][c] (bf16) <- x[b][c][y][x] (f32).
// b<2 -> xt01 (ws); b>=2 -> xtD (d_out scratch, batch-0 output region).
// ---------------------------------------------------------------------------
__global__ __launch_bounds__(256) void transpose_all(
    const float* __restrict__ x, ushort_t* __restrict__ xt01,
    ushort_t* __restrict__ xtD)
{
    __shared__ float sT[64][65];
    int blk = blockIdx.x;            // 4*64*4 = 1024
    int cg  = blk & 3;               // channel group of 64
    int y   = (blk >> 2) & 63;
    int b   = blk >> 8;              // 0..3
    int t   = threadIdx.x;
    int col = t & 63, r4 = t >> 6;

    const float* xp = x + (((size_t)b * C + cg * 64) * H + y) * W;
    #pragma unroll
    for (int i = 0; i < 16; ++i) {
        int cl = i * 4 + r4;
        sT[cl][col] = xp[(size_t)cl * HW + col];
    }
    __syncthreads();
    ushort_t* base = (b < 2) ? (xt01 + (size_t)b * HW * C)
                             : (xtD + (size_t)(b - 2) * HW * C);
    ushort_t* op = base + ((size_t)y * W) * C + cg * 64;
    #pragma unroll
    for (int i = 0; i < 16; ++i) {
        int xl = i * 4 + r4;
        op[(size_t)xl * C + col] = f2bf(sT[col][xl]);
    }
}

// ---------------------------------------------------------------------------
// K3: offset conv via MFMA, ALL batches, all 9 taps, final output (no
// partials).  Grid (b,ho) = 256 blocks, 256 thr (4 waves = 4 px-tiles).
// B-fragments: direct contiguous 16B loads from xt (fixed grid taps).
// ---------------------------------------------------------------------------
__global__ __launch_bounds__(256) void offconv_all(
    const ushort_t* __restrict__ xt01, const ushort_t* __restrict__ xtD,
    const ushort_t* __restrict__ wOffA, float* __restrict__ offFull)
{
    int orig = blockIdx.x;
    int r = ((orig & 7) << 5) | (orig >> 3);   // XCD swizzle, 256 blocks
    int b = r >> 6, ho = r & 63;
    int tid = threadIdx.x;
    int lane = tid & 63, wv = tid >> 6;
    int px = wv * 16 + (lane & 15);
    int cseg = (lane >> 4) * 8;

    const ushort_t* xtb = (b < 2) ? (xt01 + (size_t)b * HW * C)
                                  : (xtD + (size_t)(b - 2) * HW * C);
    const short8* wA = (const short8*)wOffA;

    f32x4 acc[2];
    acc[0] = (f32x4){0.f, 0.f, 0.f, 0.f};
    acc[1] = (f32x4){0.f, 0.f, 0.f, 0.f};

    #pragma unroll 1
    for (int tap = 0; tap < 9; ++tap) {
        int ky = tap / 3, kx = tap - ky * 3;
        int y  = ho - 1 + ky;
        int xx = px - 1 + kx;
        bool ok = ((unsigned)y < 64u) && ((unsigned)xx < 64u);
        unsigned msk = ok ? 0xffffffffu : 0u;
        int yc = min(max(y, 0), 63), xc = min(max(xx, 0), 63);
        const ushort_t* srcb = xtb + (size_t)(yc * 64 + xc) * C + cseg;

        #pragma unroll
        for (int cs = 0; cs < 8; ++cs) {
            union { u32x4 u; short8 s; } bv;
            bv.u = *(const u32x4*)(srcb + cs * 32);
            bv.u[0] &= msk; bv.u[1] &= msk; bv.u[2] &= msk; bv.u[3] &= msk;
            int ks = tap * 8 + cs;
            short8 aF0 = wA[(size_t)ks * 128 + lane];
            short8 aF1 = wA[(size_t)ks * 128 + 64 + lane];
            acc[0] = __builtin_amdgcn_mfma_f32_16x16x32_bf16(aF0, bv.s, acc[0], 0, 0, 0);
            acc[1] = __builtin_amdgcn_mfma_f32_16x16x32_bf16(aF1, bv.s, acc[1], 0, 0, 0);
        }
    }

    #pragma unroll
    for (int gt = 0; gt < 2; ++gt) {
        #pragma unroll
        for (int j = 0; j < 4; ++j) {
            int oc = gt * 16 + (lane >> 4) * 4 + j;
            if (oc < 18)
                offFull[((size_t)b * 18 + oc) * HW + ho * 64 + px] = acc[gt][j];
        }
    }
}

// ---------------------------------------------------------------------------
// K4: bilinear sample + bf16 MFMA GEMM (r10-validated structure).
// Coalesced loads + in-register blend; loads issue one full tap ahead and
// stay in flight across non-draining barriers.  3 blocks/CU.
// Grid (bl,ho,ohalf,pxh) = 512 blocks x 256 thr.
// ---------------------------------------------------------------------------
__global__ __launch_bounds__(256, 3) void deform_pair(
    const ushort_t* __restrict__ xtB, const float* __restrict__ offFull,
    const ushort_t* __restrict__ wPack, float* __restrict__ out, int pbase)
{
    __shared__ __align__(16) ushort_t sS[2][16][33][8];  // 16.9 KB
    __shared__ float sOff[18][32];                       // 2.3 KB
    __shared__ int   sBase[2][128];                      // run bases (dbuf)
    __shared__ float sWgt[2][32][4];                     // per-px nbr weights

    int orig = blockIdx.x;
    int r = ((orig & 7) << 6) | (orig >> 3);   // XCD swizzle, 512 blocks
    int bl = r >> 8, ho = (r >> 2) & 63, ohalf = (r >> 1) & 1, pxh = r & 1;
    int tid = threadIdx.x;
    int lane = tid & 63, wv = tid >> 6;        // 4 waves
    int chunk = tid & 15, rq = tid >> 4;       // staging identity, rq in [0,16)

    const ushort_t* xtb = xtB + (size_t)bl * HW * C;
    int b = pbase + bl;

    // this row's offsets for our px half
    for (int idx = tid; idx < 18 * 32; idx += 256) {
        int oc = idx >> 5, p2 = idx & 31;
        sOff[oc][p2] = offFull[((size_t)b * 18 + oc) * HW + ho * 64 + pxh * 32 + p2];
    }
    __syncthreads();

    f32x4 acc2[2][2];
    #pragma unroll
    for (int i = 0; i < 2; ++i)
        #pragma unroll
        for (int j = 0; j < 2; ++j) acc2[i][j] = (f32x4){0.f, 0.f, 0.f, 0.f};

    // run bases + per-pixel neighbor weights (validity folded in), dbuf by tap
    auto computeBase = [&](int tap, int buf) {
        if (tid < 128) {
            int n = tid >> 5, q = tid & 31;
            int ky = tap / 3, kx = tap - ky * 3;
            float offy = sOff[2 * tap][q];
            float offx = sOff[2 * tap + 1][q];
            float py  = offy + (float)(ho - 1 + ky);
            float pxf = offx + (float)(pxh * 32 + q - 1 + kx);
            float y0f = floorf(py), x0f = floorf(pxf);
            float wy1 = py - y0f, wx1 = pxf - x0f;
            int y0 = (int)y0f, x0 = (int)x0f;
            int dy = n >> 1, dx = n & 1;
            int yy = y0 + dy, xx = x0 + dx;
            float wn = (dy ? wy1 : (1.f - wy1)) * (dx ? wx1 : (1.f - wx1));
            wn *= (((unsigned)yy < 64u) ? 1.f : 0.f) * (((unsigned)xx < 64u) ? 1.f : 0.f);
            int yc = min(max(yy, 0), 63), xc = min(max(xx, 0), 63);
            sBase[buf][tid] = (yc * 64 + xc) * C;
            sWgt[buf][q][n] = wn;
        }
    };

    auto loadBases = [&](int buf, int* rb) {
        #pragma unroll
        for (int i = 0; i < 8; ++i) rb[i] = sBase[buf][i * 16 + rq];
    };

    // coalesced: 8 x 16B, run i*16+rq, channels sub*128 + chunk*8 ..
    auto issueC = [&](const int* rb, int sub, u32x4* L) {
        #pragma unroll
        for (int i = 0; i < 8; ++i)
            L[i] = *(const u32x4*)(xtb + rb[i] + sub * 128 + chunk * 8);
    };

    // in-register blend: L[2n+pxsel] = neighbor n of pixel rq + pxsel*16
    auto blendDirect = [&](const u32x4* L, const float* w, int p) {
        #pragma unroll
        for (int s = 0; s < 2; ++s) {
            unsigned pk[4];
            #pragma unroll
            for (int j = 0; j < 4; ++j) {
                float f0l = __uint_as_float(L[0 + s][j] << 16);
                float f0h = __uint_as_float(L[0 + s][j] & 0xffff0000u);
                float f1l = __uint_as_float(L[2 + s][j] << 16);
                float f1h = __uint_as_float(L[2 + s][j] & 0xffff0000u);
                float f2l = __uint_as_float(L[4 + s][j] << 16);
                float f2h = __uint_as_float(L[4 + s][j] & 0xffff0000u);
                float f3l = __uint_as_float(L[6 + s][j] << 16);
                float f3h = __uint_as_float(L[6 + s][j] & 0xffff0000u);
                float w0 = w[s * 4 + 0], w1 = w[s * 4 + 1];
                float w2 = w[s * 4 + 2], w3 = w[s * 4 + 3];
                float lo = fmaf(w0, f0l, fmaf(w1, f1l, fmaf(w2, f2l, w3 * f3l)));
                float hi = fmaf(w0, f0h, fmaf(w1, f1h, fmaf(w2, f2h, w3 * f3h)));
                asm("v_cvt_pk_bf16_f32 %0, %1, %2" : "=v"(pk[j]) : "v"(lo), "v"(hi));
            }
            u32x4 wvec = (u32x4){pk[0], pk[1], pk[2], pk[3]};
            *(u32x4*)&sS[p][chunk][rq + s * 16][0] = wvec;
        }
    };

    int gt0 = ohalf * 8 + wv * 2;
    const short8* wpB = (const short8*)wPack;

    auto loadA = [&](int ks4base, short8* A) {   // 8 A-frags for one sub
        #pragma unroll
        for (int h = 0; h < 4; ++h) {
            size_t an = ((size_t)(ks4base + h) * 16 + gt0) * 64 + lane;
            A[2 * h]     = wpB[an];
            A[2 * h + 1] = wpB[an + 64];
        }
    };

    auto mfmaPhase = [&](const short8* A, int p) {
        #pragma unroll
        for (int h = 0; h < 4; ++h) {
            #pragma unroll
            for (int pt = 0; pt < 2; ++pt) {
                short8 bF = *(const short8*)&sS[p][h * 4 + (lane >> 4)][pt * 16 + (lane & 15)][0];
                acc2[0][pt] = __builtin_amdgcn_mfma_f32_16x16x32_bf16(A[2 * h],     bF, acc2[0][pt], 0, 0, 0);
                acc2[1][pt] = __builtin_amdgcn_mfma_f32_16x16x32_bf16(A[2 * h + 1], bF, acc2[1][pt], 0, 0, 0);
            }
        }
    };

    u32x4 LA[8], LB[8];
    short8 A0[8], A1[8];

    // prologue
    computeBase(0, 0);
    block_sync_lds();
    {
        int rb0[8];
        loadBases(0, rb0);
        issueC(rb0, 0, LA);
        issueC(rb0, 1, LB);
    }
    loadA(0, A0);

    int p = 0;
    #pragma unroll 1
    for (int tap = 0; tap < 9; ++tap) {
        // weights for this tap (pixels rq and rq+16), written during tap-1
        float wcur[8];
        *(float4*)&wcur[0] = *(const float4*)&sWgt[tap & 1][rq][0];
        *(float4*)&wcur[4] = *(const float4*)&sWgt[tap & 1][rq + 16][0];
        if (tap < 8) computeBase(tap + 1, (tap + 1) & 1);

        int rb[8];
        // ---- sub 0 ----
        blendDirect(LA, wcur, p);
        block_sync_lds();                               // sS[p] + next bases visible
        if (tap < 8) { loadBases((tap + 1) & 1, rb); issueC(rb, 0, LA); }
        loadA(tap * 8 + 4, A1);
        mfmaPhase(A0, p);
        p ^= 1;
        // ---- sub 1 ----
        blendDirect(LB, wcur, p);
        block_sync_lds();
        if (tap < 8) { issueC(rb, 1, LB); loadA((tap + 1) * 8, A0); }
        mfmaPhase(A1, p);
        p ^= 1;
    }

    // epilogue: D[row=(l>>4)*4+j][col=l&15]
    #pragma unroll
    for (int ot = 0; ot < 2; ++ot) {
        int o = ohalf * 128 + wv * 32 + ot * 16 + (lane >> 4) * 4;
        #pragma unroll
        for (int pt = 0; pt < 2; ++pt) {
            int pxx = pxh * 32 + pt * 16 + (lane & 15);
            #pragma unroll
            for (int j = 0; j < 4; ++j)
                out[(((size_t)b * OCH + (o + j)) * H + ho) * W + pxx] = acc2[ot][pt][j];
        }
    }
}

// ---------------------------------------------------------------------------
extern "C" void kernel_launch(void* const* d_in, const int* in_sizes, int n_in,
                              void* d_out, int out_size, void* d_ws, size_t ws_size,
                              hipStream_t stream)
{
    const float* x     = (const float*)d_in[0];
    const float* w_off = (const float*)d_in[1];
    const float* w_def = (const float*)d_in[2];
    float* out = (float*)d_out;

    // ws: xt01[4.19MB] | wPack[1.18MB] | wOffA[147KB] | offFull[1.18MB]
    // total 6,701,056 B (proven size).  xt23 (4,194,304 B) lives in d_out's
    // batch-0 output region: written by transpose_all, read by offconv_all
    // and deform(pbase=2) (which writes only out[b2,b3]), then legally
    // overwritten by deform(pbase=0)'s out[b0] stores.
    ushort_t* xt01    = (ushort_t*)d_ws;
    ushort_t* wPack   = xt01 + (size_t)2 * HW * C;
    ushort_t* wOffA   = wPack + (size_t)NHS * 16 * 64 * 8;
    float*    offFull = (float*)(wOffA + (size_t)NHS * 2 * 64 * 8);
    ushort_t* xtD     = (ushort_t*)d_out;   // batch 2,3 xt scratch

    pack_all<<<(NHS * 16 * 64 + NHS * 2 * 64 + 255) / 256, 256, 0, stream>>>(
        w_def, w_off, wPack, wOffA);
    transpose_all<<<1024, 256, 0, stream>>>(x, xt01, xtD);
    offconv_all<<<256, 256, 0, stream>>>(xt01, xtD, wOffA, offFull);
    deform_pair<<<512, 256, 0, stream>>>(xtD, offFull, wPack, out, 2);
    deform_pair<<<512, 256, 0, stream>>>(xt01, offFull, wPack, out, 0);
}

// Round 12
// 96.448 us; speedup vs baseline: 1.6258x; 1.6258x over previous
//
#include <hip/hip_runtime.h>

typedef __attribute__((ext_vector_type(8))) short short8;
typedef __attribute__((ext_vector_type(4))) float f32x4;
typedef __attribute__((ext_vector_type(4))) unsigned int u32x4;
typedef unsigned short ushort_t;

constexpr int B   = 4;
constexpr int C   = 256;
constexpr int H   = 64;
constexpr int W   = 64;
constexpr int HW  = H * W;          // 4096
constexpr int OCH = 256;
constexpr int KT  = 9 * C;          // 2304, k order: k = tap*256 + c
constexpr int NHS = KT / 32;        // 72 half-steps (MFMA K=32)

__device__ __forceinline__ ushort_t f2bf(float f) {
    unsigned u = __float_as_uint(f);
    u += 0x7FFF + ((u >> 16) & 1);      // RNE
    return (ushort_t)(u >> 16);
}

// Barrier that does NOT drain vmcnt: LDS writes are made visible
// (lgkmcnt(0)), but in-register global loads stay in flight across it.
__device__ __forceinline__ void block_sync_lds() {
    asm volatile("s_waitcnt lgkmcnt(0)" ::: "memory");
    __builtin_amdgcn_s_barrier();
    asm volatile("" ::: "memory");
}

// ---------------------------------------------------------------------------
// K1: merged weight packing.
//  tid < 73728 : wPack  (w_def A-fragment order, validated rounds 2-10)
//  else        : wOffA  (w_off A-fragment order, M padded 18->32)
// ---------------------------------------------------------------------------
__global__ __launch_bounds__(256) void pack_all(
    const float* __restrict__ w_def, const float* __restrict__ w_off,
    ushort_t* __restrict__ wPack, ushort_t* __restrict__ wOffA)
{
    int tid = blockIdx.x * 256 + threadIdx.x;
    if (tid < NHS * 16 * 64) {
        int lane = tid & 63;
        int o = ((tid >> 6) & 15) * 16 + (lane & 15);
        int kbase = (tid >> 10) * 32 + (lane >> 4) * 8;
        union { ushort_t u[8]; short8 v; } pk;
        #pragma unroll
        for (int j = 0; j < 8; ++j) {
            int kidx = kbase + j;
            int c = kidx & 255, tap = kidx >> 8;
            pk.u[j] = f2bf(w_def[((size_t)o * C + c) * 9 + tap]);
        }
        *(short8*)(wPack + (size_t)tid * 8) = pk.v;
    } else {
        int t2 = tid - NHS * 16 * 64;
        if (t2 >= NHS * 2 * 64) return;
        int lane = t2 & 63;
        int o = ((t2 >> 6) & 1) * 16 + (lane & 15);
        int kbase = (t2 >> 7) * 32 + (lane >> 4) * 8;
        union { ushort_t u[8]; short8 v; } pk;
        #pragma unroll
        for (int j = 0; j < 8; ++j) {
            int kidx = kbase + j;
            int c = kidx & 255, tap = kidx >> 8;
            pk.u[j] = (o < 18) ? f2bf(w_off[((size_t)o * C + c) * 9 + tap]) : (ushort_t)0;
        }
        *(short8*)(wOffA + (size_t)t2 * 8) = pk.v;
    }
}

// ---------------------------------------------------------------------------
// K0: transpose ALL batches: xt[b][y][x][c] (bf16) <- x[b][c][y][x] (f32).
// b<2 -> xt01 (ws); b>=2 -> xtD (d_out scratch, batch-0 output region).
// ---------------------------------------------------------------------------
__global__ __launch_bounds__(256) void transpose_all(
    const float* __restrict__ x, ushort_t* __restrict__ xt01,
    ushort_t* __restrict__ xtD)
{
    __shared__ float sT[64][65];
    int blk = blockIdx.x;            // 4*64*4 = 1024
    int cg  = blk & 3;               // channel group of 64
    int y   = (blk >> 2) & 63;
    int b   = blk >> 8;              // 0..3
    int t   = threadIdx.x;
    int col = t & 63, r4 = t >> 6;

    const float* xp = x + (((size_t)b * C + cg * 64) * H + y) * W;
    #pragma unroll
    for (int i = 0; i < 16; ++i) {
        int cl = i * 4 + r4;
        sT[cl][col] = xp[(size_t)cl * HW + col];
    }
    __syncthreads();
    ushort_t* base = (b < 2) ? (xt01 + (size_t)b * HW * C)
                             : (xtD + (size_t)(b - 2) * HW * C);
    ushort_t* op = base + ((size_t)y * W) * C + cg * 64;
    #pragma unroll
    for (int i = 0; i < 16; ++i) {
        int xl = i * 4 + r4;
        op[(size_t)xl * C + col] = f2bf(sT[col][xl]);
    }
}

// ---------------------------------------------------------------------------
// K3: offset conv via MFMA, ALL batches, all 9 taps, final output (no
// partials).  Grid (b,ho) = 256 blocks, 256 thr (4 waves = 4 px-tiles).
// B-fragments: direct contiguous 16B loads from xt (fixed grid taps).
// ---------------------------------------------------------------------------
__global__ __launch_bounds__(256) void offconv_all(
    const ushort_t* __restrict__ xt01, const ushort_t* __restrict__ xtD,
    const ushort_t* __restrict__ wOffA, float* __restrict__ offFull)
{
    int orig = blockIdx.x;
    int r = ((orig & 7) << 5) | (orig >> 3);   // XCD swizzle, 256 blocks
    int b = r >> 6, ho = r & 63;
    int tid = threadIdx.x;
    int lane = tid & 63, wv = tid >> 6;
    int px = wv * 16 + (lane & 15);
    int cseg = (lane >> 4) * 8;

    const ushort_t* xtb = (b < 2) ? (xt01 + (size_t)b * HW * C)
                                  : (xtD + (size_t)(b - 2) * HW * C);
    const short8* wA = (const short8*)wOffA;

    f32x4 acc[2];
    acc[0] = (f32x4){0.f, 0.f, 0.f, 0.f};
    acc[1] = (f32x4){0.f, 0.f, 0.f, 0.f};

    #pragma unroll 1
    for (int tap = 0; tap < 9; ++tap) {
        int ky = tap / 3, kx = tap - ky * 3;
        int y  = ho - 1 + ky;
        int xx = px - 1 + kx;
        bool ok = ((unsigned)y < 64u) && ((unsigned)xx < 64u);
        unsigned msk = ok ? 0xffffffffu : 0u;
        int yc = min(max(y, 0), 63), xc = min(max(xx, 0), 63);
        const ushort_t* srcb = xtb + (size_t)(yc * 64 + xc) * C + cseg;

        #pragma unroll
        for (int cs = 0; cs < 8; ++cs) {
            union { u32x4 u; short8 s; } bv;
            bv.u = *(const u32x4*)(srcb + cs * 32);
            bv.u[0] &= msk; bv.u[1] &= msk; bv.u[2] &= msk; bv.u[3] &= msk;
            int ks = tap * 8 + cs;
            short8 aF0 = wA[(size_t)ks * 128 + lane];
            short8 aF1 = wA[(size_t)ks * 128 + 64 + lane];
            acc[0] = __builtin_amdgcn_mfma_f32_16x16x32_bf16(aF0, bv.s, acc[0], 0, 0, 0);
            acc[1] = __builtin_amdgcn_mfma_f32_16x16x32_bf16(aF1, bv.s, acc[1], 0, 0, 0);
        }
    }

    #pragma unroll
    for (int gt = 0; gt < 2; ++gt) {
        #pragma unroll
        for (int j = 0; j < 4; ++j) {
            int oc = gt * 16 + (lane >> 4) * 4 + j;
            if (oc < 18)
                offFull[((size_t)b * 18 + oc) * HW + ho * 64 + px] = acc[gt][j];
        }
    }
}

// ---------------------------------------------------------------------------
// K4: bilinear sample + bf16 MFMA GEMM (r10-validated structure and
// occupancy: __launch_bounds__(256,2), VGPR ~110-130, NO spills).
// Coalesced loads + in-register blend; loads issue one full tap ahead and
// stay in flight across non-draining barriers.
// Grid (bl,ho,ohalf,pxh) = 512 blocks x 256 thr.
// ---------------------------------------------------------------------------
__global__ __launch_bounds__(256, 2) void deform_pair(
    const ushort_t* __restrict__ xtB, const float* __restrict__ offFull,
    const ushort_t* __restrict__ wPack, float* __restrict__ out, int pbase)
{
    __shared__ __align__(16) ushort_t sS[2][16][33][8];  // 16.9 KB
    __shared__ float sOff[18][32];                       // 2.3 KB
    __shared__ int   sBase[2][128];                      // run bases (dbuf)
    __shared__ float sWgt[2][32][4];                     // per-px nbr weights

    int orig = blockIdx.x;
    int r = ((orig & 7) << 6) | (orig >> 3);   // XCD swizzle, 512 blocks
    int bl = r >> 8, ho = (r >> 2) & 63, ohalf = (r >> 1) & 1, pxh = r & 1;
    int tid = threadIdx.x;
    int lane = tid & 63, wv = tid >> 6;        // 4 waves
    int chunk = tid & 15, rq = tid >> 4;       // staging identity, rq in [0,16)

    const ushort_t* xtb = xtB + (size_t)bl * HW * C;
    int b = pbase + bl;

    // this row's offsets for our px half
    for (int idx = tid; idx < 18 * 32; idx += 256) {
        int oc = idx >> 5, p2 = idx & 31;
        sOff[oc][p2] = offFull[((size_t)b * 18 + oc) * HW + ho * 64 + pxh * 32 + p2];
    }
    __syncthreads();

    f32x4 acc2[2][2];
    #pragma unroll
    for (int i = 0; i < 2; ++i)
        #pragma unroll
        for (int j = 0; j < 2; ++j) acc2[i][j] = (f32x4){0.f, 0.f, 0.f, 0.f};

    // run bases + per-pixel neighbor weights (validity folded in), dbuf by tap
    auto computeBase = [&](int tap, int buf) {
        if (tid < 128) {
            int n = tid >> 5, q = tid & 31;
            int ky = tap / 3, kx = tap - ky * 3;
            float offy = sOff[2 * tap][q];
            float offx = sOff[2 * tap + 1][q];
            float py  = offy + (float)(ho - 1 + ky);
            float pxf = offx + (float)(pxh * 32 + q - 1 + kx);
            float y0f = floorf(py), x0f = floorf(pxf);
            float wy1 = py - y0f, wx1 = pxf - x0f;
            int y0 = (int)y0f, x0 = (int)x0f;
            int dy = n >> 1, dx = n & 1;
            int yy = y0 + dy, xx = x0 + dx;
            float wn = (dy ? wy1 : (1.f - wy1)) * (dx ? wx1 : (1.f - wx1));
            wn *= (((unsigned)yy < 64u) ? 1.f : 0.f) * (((unsigned)xx < 64u) ? 1.f : 0.f);
            int yc = min(max(yy, 0), 63), xc = min(max(xx, 0), 63);
            sBase[buf][tid] = (yc * 64 + xc) * C;
            sWgt[buf][q][n] = wn;
        }
    };

    auto loadBases = [&](int buf, int* rb) {
        #pragma unroll
        for (int i = 0; i < 8; ++i) rb[i] = sBase[buf][i * 16 + rq];
    };

    // coalesced: 8 x 16B, run i*16+rq, channels sub*128 + chunk*8 ..
    auto issueC = [&](const int* rb, int sub, u32x4* L) {
        #pragma unroll
        for (int i = 0; i < 8; ++i)
            L[i] = *(const u32x4*)(xtb + rb[i] + sub * 128 + chunk * 8);
    };

    // in-register blend: L[2n+pxsel] = neighbor n of pixel rq + pxsel*16
    auto blendDirect = [&](const u32x4* L, const float* w, int p) {
        #pragma unroll
        for (int s = 0; s < 2; ++s) {
            unsigned pk[4];
            #pragma unroll
            for (int j = 0; j < 4; ++j) {
                float f0l = __uint_as_float(L[0 + s][j] << 16);
                float f0h = __uint_as_float(L[0 + s][j] & 0xffff0000u);
                float f1l = __uint_as_float(L[2 + s][j] << 16);
                float f1h = __uint_as_float(L[2 + s][j] & 0xffff0000u);
                float f2l = __uint_as_float(L[4 + s][j] << 16);
                float f2h = __uint_as_float(L[4 + s][j] & 0xffff0000u);
                float f3l = __uint_as_float(L[6 + s][j] << 16);
                float f3h = __uint_as_float(L[6 + s][j] & 0xffff0000u);
                float w0 = w[s * 4 + 0], w1 = w[s * 4 + 1];
                float w2 = w[s * 4 + 2], w3 = w[s * 4 + 3];
                float lo = fmaf(w0, f0l, fmaf(w1, f1l, fmaf(w2, f2l, w3 * f3l)));
                float hi = fmaf(w0, f0h, fmaf(w1, f1h, fmaf(w2, f2h, w3 * f3h)));
                asm("v_cvt_pk_bf16_f32 %0, %1, %2" : "=v"(pk[j]) : "v"(lo), "v"(hi));
            }
            u32x4 wvec = (u32x4){pk[0], pk[1], pk[2], pk[3]};
            *(u32x4*)&sS[p][chunk][rq + s * 16][0] = wvec;
        }
    };

    int gt0 = ohalf * 8 + wv * 2;
    const short8* wpB = (const short8*)wPack;

    auto loadA = [&](int ks4base, short8* A) {   // 8 A-frags for one sub
        #pragma unroll
        for (int h = 0; h < 4; ++h) {
            size_t an = ((size_t)(ks4base + h) * 16 + gt0) * 64 + lane;
            A[2 * h]     = wpB[an];
            A[2 * h + 1] = wpB[an + 64];
        }
    };

    auto mfmaPhase = [&](const short8* A, int p) {
        #pragma unroll
        for (int h = 0; h < 4; ++h) {
            #pragma unroll
            for (int pt = 0; pt < 2; ++pt) {
                short8 bF = *(const short8*)&sS[p][h * 4 + (lane >> 4)][pt * 16 + (lane & 15)][0];
                acc2[0][pt] = __builtin_amdgcn_mfma_f32_16x16x32_bf16(A[2 * h],     bF, acc2[0][pt], 0, 0, 0);
                acc2[1][pt] = __builtin_amdgcn_mfma_f32_16x16x32_bf16(A[2 * h + 1], bF, acc2[1][pt], 0, 0, 0);
            }
        }
    };

    u32x4 LA[8], LB[8];
    short8 A0[8], A1[8];

    // prologue
    computeBase(0, 0);
    block_sync_lds();
    {
        int rb0[8];
        loadBases(0, rb0);
        issueC(rb0, 0, LA);
        issueC(rb0, 1, LB);
    }
    loadA(0, A0);

    int p = 0;
    #pragma unroll 1
    for (int tap = 0; tap < 9; ++tap) {
        // weights for this tap (pixels rq and rq+16), written during tap-1
        float wcur[8];
        *(float4*)&wcur[0] = *(const float4*)&sWgt[tap & 1][rq][0];
        *(float4*)&wcur[4] = *(const float4*)&sWgt[tap & 1][rq + 16][0];
        if (tap < 8) computeBase(tap + 1, (tap + 1) & 1);

        int rb[8];
        // ---- sub 0 ----
        blendDirect(LA, wcur, p);
        block_sync_lds();                               // sS[p] + next bases visible
        if (tap < 8) { loadBases((tap + 1) & 1, rb); issueC(rb, 0, LA); }
        loadA(tap * 8 + 4, A1);
        mfmaPhase(A0, p);
        p ^= 1;
        // ---- sub 1 ----
        blendDirect(LB, wcur, p);
        block_sync_lds();
        if (tap < 8) { issueC(rb, 1, LB); loadA((tap + 1) * 8, A0); }
        mfmaPhase(A1, p);
        p ^= 1;
    }

    // epilogue: D[row=(l>>4)*4+j][col=l&15]
    #pragma unroll
    for (int ot = 0; ot < 2; ++ot) {
        int o = ohalf * 128 + wv * 32 + ot * 16 + (lane >> 4) * 4;
        #pragma unroll
        for (int pt = 0; pt < 2; ++pt) {
            int pxx = pxh * 32 + pt * 16 + (lane & 15);
            #pragma unroll
            for (int j = 0; j < 4; ++j)
                out[(((size_t)b * OCH + (o + j)) * H + ho) * W + pxx] = acc2[ot][pt][j];
        }
    }
}

// ---------------------------------------------------------------------------
extern "C" void kernel_launch(void* const* d_in, const int* in_sizes, int n_in,
                              void* d_out, int out_size, void* d_ws, size_t ws_size,
                              hipStream_t stream)
{
    const float* x     = (const float*)d_in[0];
    const float* w_off = (const float*)d_in[1];
    const float* w_def = (const float*)d_in[2];
    float* out = (float*)d_out;

    // ws: xt01[4.19MB] | wPack[1.18MB] | wOffA[147KB] | offFull[1.18MB]
    // total 6,701,056 B (proven size).  xt23 (4,194,304 B) lives in d_out's
    // batch-0 output region: written by transpose_all, read by offconv_all
    // and deform(pbase=2) (which writes only out[b2,b3]), then legally
    // overwritten by deform(pbase=0)'s out[b0] stores.
    ushort_t* xt01    = (ushort_t*)d_ws;
    ushort_t* wPack   = xt01 + (size_t)2 * HW * C;
    ushort_t* wOffA   = wPack + (size_t)NHS * 16 * 64 * 8;
    float*    offFull = (float*)(wOffA + (size_t)NHS * 2 * 64 * 8);
    ushort_t* xtD     = (ushort_t*)d_out;   // batch 2,3 xt scratch

    pack_all<<<(NHS * 16 * 64 + NHS * 2 * 64 + 255) / 256, 256, 0, stream>>>(
        w_def, w_off, wPack, wOffA);
    transpose_all<<<1024, 256, 0, stream>>>(x, xt01, xtD);
    offconv_all<<<256, 256, 0, stream>>>(xt01, xtD, wOffA, offFull);
    deform_pair<<<512, 256, 0, stream>>>(xtD, offFull, wPack, out, 2);
    deform_pair<<<512, 256, 0, stream>>>(xt01, offFull, wPack, out, 0);
}